// Round 22
// baseline (534.772 us; speedup 1.0000x reference)
//
#include <hip/hip_runtime.h>
#include <hip/hip_bf16.h>
#include <math.h>

#define BB 32
#define TT 12
#define NN 512
#define HH 64
#define DIN 65
#define MSUB 96
#define RTOT 16384
#define BSTG 8192      // f16 per B staging buffer (16 subtiles x 512), BK=128
#define WOFFG 24576    // 3*BSTG: W region base in gates lds (f16 units)

typedef _Float16 f16;
typedef f16 f16x4 __attribute__((ext_vector_type(4)));
typedef f16 f16x8 __attribute__((ext_vector_type(8)));
typedef float f32x4 __attribute__((ext_vector_type(4)));

#define GLD_LDS16(g, l) \
    __builtin_amdgcn_global_load_lds((const __attribute__((address_space(1))) void*)(g), \
                                     (__attribute__((address_space(3))) void*)(l), 16, 0, 0)

// Bf element address: node j (K-dim), batch b, h-col q in [0,64)
__device__ __forceinline__ size_t bf_addr(int j, int b, int q) {
    return ((size_t)(((j >> 5) * 32 + b) * 4 + (q >> 4)) * 64 + ((j >> 3) & 3) * 16 + (q & 15)) * 8 + (j & 7);
}

__global__ __launch_bounds__(256) void conv_a(const float* __restrict__ P, f16* __restrict__ Af) {
    int u = blockIdx.x * 256 + threadIdx.x;
    int lane = u & 63;
    int su = u >> 6;
    int ks = su / MSUB, ms = su - ks * MSUB;
    int m = ms * 16 + (lane & 15);
    int k = ks * 32 + (lane >> 4) * 8;
    const float* src = &P[(size_t)m * 512 + k];
    f16x8 v;
#pragma unroll
    for (int i = 0; i < 8; ++i) v[i] = (f16)src[i];
    *(f16x8*)&Af[(size_t)u * 8] = v;
}

// W pack, h-rows only: K'=192 (6 slots), f = 2s+(i>=4) = kl*4+ps, q = ps*16+4g+(i&3)
__global__ __launch_bounds__(256) void conv_w2(const float* __restrict__ W, int O, int OS,
                                               f16* __restrict__ Wf) {
    int u = blockIdx.x * 256 + threadIdx.x;
    if (u >= 6 * OS * 64) return;
    int lane = u & 63, slot = u >> 6;
    int s = slot / OS, os = slot - s * OS;
    int o = os * 16 + (lane & 15);
    int g = lane >> 4;
    f16x8 v;
#pragma unroll
    for (int i = 0; i < 8; ++i) {
        int f = 2 * s + (i >= 4 ? 1 : 0);
        int kl = f >> 2, ps = f & 3;
        int q = ps * 16 + 4 * g + (i & 3);
        v[i] = (f16)W[(size_t)(kl * 65 + 1 + q) * O + o];
    }
    *(f16x8*)&Wf[(size_t)u * 8] = v;
}

// pack X (all 12 t) fragment-major: cols c = t*32+b (24 subtiles), rows j
__global__ __launch_bounds__(256) void conv_x(const float* __restrict__ x, f16* __restrict__ Xf) {
    int u = blockIdx.x * 256 + threadIdx.x;  // 24576 slots
    int lane = u & 63;
    int su = u >> 6;
    int ks = su / 24, cs = su - ks * 24;
    int c = cs * 16 + (lane & 15);
    int t = c >> 5, b = c & 31;
    int j0 = ks * 32 + (lane >> 4) * 8;
    f16x8 v;
#pragma unroll
    for (int i = 0; i < 8; ++i) v[i] = (f16)x[((size_t)b * TT + t) * NN + j0 + i];
    *(f16x8*)&Xf[(size_t)u * 8] = v;
}

// xc[t][b][n][k] = (G_k @ x_t)[n,b]; grid 24 blocks x 4 waves (96 msubs)
__global__ __launch_bounds__(256, 1) void xc_mm(const f16* __restrict__ Af,
                                                const f16* __restrict__ Xf,
                                                float* __restrict__ xc) {
    int tid = threadIdx.x, wave = tid >> 6, lane = tid & 63;
    int msub = blockIdx.x * 4 + wave;
    f32x4 acc[24] = {};
#pragma unroll 1
    for (int ks = 0; ks < 16; ++ks) {
        f16x8 af = *(const f16x8*)&Af[((size_t)(ks * MSUB + msub) * 64 + lane) * 8];
#pragma unroll
        for (int cs = 0; cs < 24; ++cs) {
            f16x8 bf = *(const f16x8*)&Xf[((size_t)(ks * 24 + cs) * 64 + lane) * 8];
            acc[cs] = __builtin_amdgcn_mfma_f32_16x16x32_f16(bf, af, acc[cs], 0, 0, 0);
        }
    }
    int grow = msub * 16 + (lane & 15);
    int k = grow >> 9, n = grow & 511;
    int g = lane >> 4;
#pragma unroll
    for (int cs = 0; cs < 24; ++cs)
#pragma unroll
        for (int rI = 0; rI < 4; ++rI) {
            int c = cs * 16 + 4 * g + rI;  // t*32+b
            xc[((size_t)c * 512 + n) * 4 + k] = acc[cs][rI];
        }
}

// rs[k*512+n] = rowsum of G_k
__global__ __launch_bounds__(256) void rs_k(const float* __restrict__ P, float* __restrict__ rs) {
    int r = blockIdx.x * 256 + threadIdx.x;
    if (r >= 1536) return;
    const float4* row = (const float4*)&P[(size_t)r * 512];
    float s = 0.f;
    for (int i = 0; i < 128; ++i) { float4 v = row[i]; s += v.x + v.y + v.z + v.w; }
    rs[r] = s;
}

// B staging: 16 subtiles (K128-step), uniform 4 per wave
__device__ __forceinline__ void stage_b(const f16* __restrict__ BfIn, f16* __restrict__ lds,
                                        int b, int wave, int lane, int buf, int it) {
#pragma unroll
    for (int qi = 0; qi < 4; ++qi) {
        int q = qi * 4 + wave;  // 0..15
        int ksl = q >> 2, ps = q & 3;
        const f16* src = &BfIn[((size_t)(((it * 4 + ksl) * 32 + b) * 4 + ps) * 64 + lane) * 8];
        GLD_LDS16(src, &lds[buf * BSTG + q * 512 + lane * 8]);
    }
}

__device__ __forceinline__ void load_a(const f16* __restrict__ Af, f16x8 (&a)[12],
                                       int mb, int wave, int lane, int it) {
#pragma unroll
    for (int s = 0; s < 4; ++s)
#pragma unroll
        for (int k = 0; k < 3; ++k)
            a[s * 3 + k] = *(const f16x8*)&Af[((size_t)((it * 4 + s) * MSUB + k * 32 + mb * 4 + wave) * 64 + lane) * 8];
}

__device__ __forceinline__ void compute_step(const f16* __restrict__ lds, int buf, int lane,
                                             const f16x8 (&a)[12], f32x4 (&acc)[12]) {
#pragma unroll
    for (int s = 0; s < 4; ++s) {
        f16x8 bfr[4];
#pragma unroll
        for (int ps = 0; ps < 4; ++ps)
            bfr[ps] = *(const f16x8*)&lds[buf * BSTG + (s * 4 + ps) * 512 + lane * 8];
#pragma unroll
        for (int k = 0; k < 3; ++k)
#pragma unroll
            for (int ps = 0; ps < 4; ++ps)
                acc[k * 4 + ps] = __builtin_amdgcn_mfma_f32_16x16x32_f16(bfr[ps], a[s * 3 + k], acc[k * 4 + ps], 0, 0, 0);
    }
}

// BK=128: 4 steps, 3-buffer staging, counted vmcnt(12) (newest 12 = next A-loads), raw barrier.
__device__ __forceinline__ void gcn_mm(const f16* __restrict__ Af,
                                       const f16* __restrict__ BfIn,
                                       f16* __restrict__ lds,
                                       int b, int mb, int wave, int lane,
                                       f32x4 (&acc)[12]) {
    f16x8 a0[12], a1[12];
    stage_b(BfIn, lds, b, wave, lane, 0, 0);
    stage_b(BfIn, lds, b, wave, lane, 1, 1);
    load_a(Af, a0, mb, wave, lane, 0);
#pragma unroll
    for (int it = 0; it < 4; ++it) {
        asm volatile("s_waitcnt vmcnt(12)" ::: "memory");
        __builtin_amdgcn_sched_barrier(0);
        __builtin_amdgcn_s_barrier();
        __builtin_amdgcn_sched_barrier(0);
        if (it + 2 < 4) stage_b(BfIn, lds, b, wave, lane, (it + 2) % 3, it + 2);
        if (it + 1 < 4) {
            if ((it + 1) % 2 == 0) load_a(Af, a0, mb, wave, lane, it + 1);
            else                   load_a(Af, a1, mb, wave, lane, it + 1);
        }
        __builtin_amdgcn_sched_barrier(0);
        if (it % 2 == 0) compute_step(lds, it % 3, lane, a0, acc);
        else             compute_step(lds, it % 3, lane, a1, acc);
    }
}

__device__ __forceinline__ void build_ad(const f32x4 (&acc)[12], f16x8 (&ad)[6]) {
#pragma unroll
    for (int s = 0; s < 6; ++s)
#pragma unroll
        for (int i = 0; i < 4; ++i) {
            ad[s][i] = (f16)acc[2 * s][i];
            ad[s][4 + i] = (f16)acc[2 * s + 1][i];
        }
}

// pc-term helper: pct[k][rI] from pc4 table ([b][n][4] f32)
__device__ __forceinline__ void load_pct(const float* __restrict__ pc4, int b, int node0,
                                         int g, float (&pct)[3][4]) {
#pragma unroll
    for (int rI = 0; rI < 4; ++rI) {
        float4 v = *(const float4*)&pc4[((size_t)(b * 512 + node0 + 4 * g + rI)) * 4];
        pct[0][rI] = v.x; pct[1][rI] = v.y; pct[2][rI] = v.z;
    }
}

// gates: pmode 0=no p0 term, 1=pc4 (encoder xc), 2=own-acc gq (decoder c>=1); cg: write gq table
__global__ __launch_bounds__(256, 1) void fused_gates(const f16* __restrict__ Af,
                                                      const f16* __restrict__ BfIn,
                                                      f16* __restrict__ BfOut,
                                                      const f16* __restrict__ Wf,
                                                      const float* __restrict__ bias,
                                                      const float* __restrict__ hf,
                                                      float* __restrict__ zf,
                                                      const float* __restrict__ Worig,
                                                      const float* __restrict__ pc4,
                                                      int pmode,
                                                      const float* __restrict__ Wp,
                                                      const float* __restrict__ bp,
                                                      const float* __restrict__ rs,
                                                      float* __restrict__ gq,
                                                      int cg) {
    __shared__ f16 lds[WOFFG + 24576];  // 48 KB staging + 48 KB W
    int tid = threadIdx.x, wave = tid >> 6, lane = tid & 63;
    int b = blockIdx.x & 31, mb = blockIdx.x >> 5;

#pragma unroll
    for (int qi = 0; qi < 12; ++qi) {
        int q = qi * 4 + wave;  // 48 W subtiles
        GLD_LDS16(&Wf[((size_t)q * 64 + lane) * 8], &lds[WOFFG + q * 512 + lane * 8]);
    }

    f32x4 acc[12] = {};
    gcn_mm(Af, BfIn, lds, b, mb, wave, lane, acc);

    int o_l = lane & 15, g = lane >> 4;
    int node0 = mb * 64 + wave * 16;
    int rf = b * 32 + mb * 4 + wave;

    // decoder: gq[k][n=node0+l&15] = sum_q (G_k@h)[n,q]*Wp[q] + bp*rs[k][n]
    float gqf[3] = {0.f, 0.f, 0.f};
    if (cg) {
#pragma unroll
        for (int ps = 0; ps < 4; ++ps) {
            float4 wp = *(const float4*)&Wp[ps * 16 + 4 * g];
#pragma unroll
            for (int k = 0; k < 3; ++k) {
                gqf[k] += acc[k * 4 + ps][0] * wp.x + acc[k * 4 + ps][1] * wp.y
                        + acc[k * 4 + ps][2] * wp.z + acc[k * 4 + ps][3] * wp.w;
            }
        }
        float bpv = bp[0];
#pragma unroll
        for (int k = 0; k < 3; ++k) {
            gqf[k] += __shfl_xor(gqf[k], 16, 64);
            gqf[k] += __shfl_xor(gqf[k], 32, 64);
            gqf[k] += bpv * rs[k * 512 + node0 + o_l];
        }
        if (lane < 16) {
#pragma unroll
            for (int k = 0; k < 3; ++k)
                gq[((size_t)(b * 512 + node0 + lane)) * 4 + k] = gqf[k];
        }
    }

    f16x8 ad[6];
    build_ad(acc, ad);

    f32x4 acc2[8] = {};
#pragma unroll
    for (int s = 0; s < 6; ++s)
#pragma unroll
        for (int os = 0; os < 8; ++os) {
            f16x8 w = *(const f16x8*)&lds[WOFFG + (s * 8 + os) * 512 + lane * 8];
            acc2[os] = __builtin_amdgcn_mfma_f32_16x16x32_f16(ad[s], w, acc2[os], 0, 0, 0);
        }

    // p0 term
    float pct[3][4] = {};
    if (pmode == 1) load_pct(pc4, b, node0, g, pct);
    else if (pmode == 2) {
#pragma unroll
        for (int k = 0; k < 3; ++k)
#pragma unroll
            for (int rI = 0; rI < 4; ++rI)
                pct[k][rI] = __shfl(gqf[k], 4 * g + rI, 64);
    }
    if (pmode) {
#pragma unroll
        for (int os = 0; os < 8; ++os) {
            int o = os * 16 + o_l;
            float w0 = Worig[(size_t)0 * 128 + o];
            float w1 = Worig[(size_t)65 * 128 + o];
            float w2 = Worig[(size_t)130 * 128 + o];
#pragma unroll
            for (int rI = 0; rI < 4; ++rI)
                acc2[os][rI] += pct[0][rI] * w0 + pct[1][rI] * w1 + pct[2][rI] * w2;
        }
    }

#pragma unroll
    for (int os = 0; os < 4; ++os) {
        f32x4 v;
#pragma unroll
        for (int rI = 0; rI < 4; ++rI)
            v[rI] = 1.f / (1.f + expf(-(acc2[os][rI] + bias[os * 16 + o_l])));
        *(f32x4*)&zf[((size_t)(rf * 4 + os) * 64 + lane) * 4] = v;
    }
#pragma unroll
    for (int os = 4; os < 8; ++os) {
        int osh = os - 4;
        f32x4 hv = *(const f32x4*)&hf[((size_t)(rf * 4 + osh) * 64 + lane) * 4];
        f16x4 st;
#pragma unroll
        for (int rI = 0; rI < 4; ++rI) {
            float rr = 1.f / (1.f + expf(-(acc2[os][rI] + bias[64 + osh * 16 + o_l])));
            st[rI] = (f16)(rr * hv[rI]);
        }
        *(f16x4*)&BfOut[bf_addr(node0 + 4 * g, b, osh * 16 + o_l)] = st;
    }
}

// cand: pmode 0=no p0 term, 1=pc4 (xc for encoder, gq for decoder c>=1)
__global__ __launch_bounds__(256, 1) void fused_cand(const f16* __restrict__ Af,
                                                     const f16* __restrict__ BfIn,
                                                     f16* __restrict__ BfOut,
                                                     const f16* __restrict__ Wf,
                                                     const float* __restrict__ bias,
                                                     const float* __restrict__ zf,
                                                     float* __restrict__ hf,
                                                     const float* __restrict__ Worig,
                                                     const float* __restrict__ pc4,
                                                     int pmode,
                                                     const float* __restrict__ Wp,
                                                     const float* __restrict__ bp,
                                                     float* __restrict__ outp, int t, int hor,
                                                     int mode) {
    __shared__ f16 lds[WOFFG + 12288];  // 48 KB staging + 24 KB W
    int tid = threadIdx.x, wave = tid >> 6, lane = tid & 63;
    int b = blockIdx.x & 31, mb = blockIdx.x >> 5;

#pragma unroll
    for (int qi = 0; qi < 6; ++qi) {
        int q = qi * 4 + wave;  // 24 W subtiles
        GLD_LDS16(&Wf[((size_t)q * 64 + lane) * 8], &lds[WOFFG + q * 512 + lane * 8]);
    }

    f32x4 acc[12] = {};
    gcn_mm(Af, BfIn, lds, b, mb, wave, lane, acc);

    f16x8 ad[6];
    build_ad(acc, ad);

    f32x4 acc2[4] = {};
#pragma unroll
    for (int s = 0; s < 6; ++s)
#pragma unroll
        for (int os = 0; os < 4; ++os) {
            f16x8 w = *(const f16x8*)&lds[WOFFG + (s * 4 + os) * 512 + lane * 8];
            acc2[os] = __builtin_amdgcn_mfma_f32_16x16x32_f16(ad[s], w, acc2[os], 0, 0, 0);
        }

    int o_l = lane & 15, g = lane >> 4;
    int node0 = mb * 64 + wave * 16;
    int rf = b * 32 + mb * 4 + wave;

    float pct[3][4] = {};
    if (pmode == 1) load_pct(pc4, b, node0, g, pct);
    if (pmode) {
#pragma unroll
        for (int os = 0; os < 4; ++os) {
            int o = os * 16 + o_l;
            float w0 = Worig[(size_t)0 * 64 + o];
            float w1 = Worig[(size_t)65 * 64 + o];
            float w2 = Worig[(size_t)130 * 64 + o];
#pragma unroll
            for (int rI = 0; rI < 4; ++rI)
                acc2[os][rI] += pct[0][rI] * w0 + pct[1][rI] * w1 + pct[2][rI] * w2;
        }
    }

    float pp[4] = {0.f, 0.f, 0.f, 0.f};
#pragma unroll
    for (int os = 0; os < 4; ++os) {
        int o = os * 16 + o_l;
        float wp = mode ? Wp[o] : 0.f;
        f32x4 zv = *(const f32x4*)&zf[((size_t)(rf * 4 + os) * 64 + lane) * 4];
        f32x4 hv = *(const f32x4*)&hf[((size_t)(rf * 4 + os) * 64 + lane) * 4];
        f32x4 hn;
        f16x4 st;
#pragma unroll
        for (int rI = 0; rI < 4; ++rI) {
            float hc = tanhf(acc2[os][rI] + bias[o]);
            hn[rI] = (1.f - zv[rI]) * hv[rI] + zv[rI] * hc;
            pp[rI] += hn[rI] * wp;
            st[rI] = (f16)hn[rI];
        }
        *(f32x4*)&hf[((size_t)(rf * 4 + os) * 64 + lane) * 4] = hn;
        *(f16x4*)&BfOut[bf_addr(node0 + 4 * g, b, o)] = st;
    }
    if (mode) {
#pragma unroll
        for (int m = 1; m < 16; m <<= 1)
#pragma unroll
            for (int rI = 0; rI < 4; ++rI) pp[rI] += __shfl_xor(pp[rI], m, 64);
        if (o_l == 0) {
            int n0 = node0 + 4 * g;
            float4 ov;
            ov.x = pp[0] + bp[0]; ov.y = pp[1] + bp[0];
            ov.z = pp[2] + bp[0]; ov.w = pp[3] + bp[0];
            *(float4*)&outp[((size_t)b * hor + t) * NN + n0] = ov;
        }
    }
}

extern "C" void kernel_launch(void* const* d_in, const int* in_sizes, int n_in,
                              void* d_out, int out_size, void* d_ws, size_t ws_size,
                              hipStream_t stream) {
    const float* x   = (const float*)d_in[0];
    const float* P   = (const float*)d_in[1];
    const float* Weg = (const float*)d_in[2];
    const float* beg = (const float*)d_in[3];
    const float* Weu = (const float*)d_in[4];
    const float* beu = (const float*)d_in[5];
    const float* Wdg = (const float*)d_in[6];
    const float* bdg = (const float*)d_in[7];
    const float* Wdu = (const float*)d_in[8];
    const float* bdu = (const float*)d_in[9];
    const float* Wp  = (const float*)d_in[10];
    const float* bp  = (const float*)d_in[11];
    float* out = (float*)d_out;
    int hor = out_size / (BB * NN);

    float* ws = (float*)d_ws;
    size_t off = 0;
    float* hf = ws + off; off += (size_t)RTOT * HH;
    float* zf = ws + off; off += (size_t)RTOT * HH;
    float* xc = ws + off; off += (size_t)12 * 32 * 512 * 4;   // 3 MB
    float* gq = ws + off; off += (size_t)32 * 512 * 4;        // 256 KB
    float* rs = ws + off; off += 2048;
    f16* BfA  = (f16*)(ws + off); off += (size_t)16 * 32 * 4 * 64 * 8 / 2;  // 2 MB
    f16* BfB  = (f16*)(ws + off); off += (size_t)16 * 32 * 4 * 64 * 8 / 2;
    f16* Af   = (f16*)(ws + off); off += (size_t)MSUB * 16 * 512 / 2;
    f16* Xf   = (f16*)(ws + off); off += (size_t)512 * 384 / 2;
    f16* WfGe = (f16*)(ws + off); off += 6 * 8 * 64 * 8 / 2;
    f16* WfGd = (f16*)(ws + off); off += 6 * 8 * 64 * 8 / 2;
    f16* WfCe = (f16*)(ws + off); off += 6 * 4 * 64 * 8 / 2;
    f16* WfCd = (f16*)(ws + off); off += 6 * 4 * 64 * 8 / 2;

    size_t bf_bytes = (size_t)16 * 32 * 4 * 64 * 8 * sizeof(f16);
    hipMemsetAsync(hf, 0, (size_t)RTOT * HH * sizeof(float), stream);
    hipMemsetAsync(BfA, 0, bf_bytes, stream);
    hipMemsetAsync(BfB, 0, bf_bytes, stream);

    conv_a<<<(MSUB * 16 * 512 / 8) / 256, 256, 0, stream>>>(P, Af);
    conv_w2<<<12, 256, 0, stream>>>(Weg, 128, 8, WfGe);
    conv_w2<<<12, 256, 0, stream>>>(Wdg, 128, 8, WfGd);
    conv_w2<<<6,  256, 0, stream>>>(Weu, 64, 4, WfCe);
    conv_w2<<<6,  256, 0, stream>>>(Wdu, 64, 4, WfCd);
    conv_x<<<96, 256, 0, stream>>>(x, Xf);
    xc_mm<<<24, 256, 0, stream>>>(Af, Xf, xc);
    rs_k<<<6, 256, 0, stream>>>(P, rs);

    for (int t = 0; t < TT; ++t) {
        const float* xct = xc + (size_t)t * 32 * 512 * 4;
        fused_gates<<<256, 256, 0, stream>>>(Af, BfA, BfB, WfGe, beg, hf, zf,
                                             Weg, xct, 1, Wp, bp, rs, gq, 0);
        fused_cand<<<256, 256, 0, stream>>>(Af, BfB, BfA, WfCe, beu, zf, hf,
                                            Weu, xct, 1, Wp, bp, out, 0, hor, 0);
    }
    for (int c = 0; c < hor; ++c) {
        fused_gates<<<256, 256, 0, stream>>>(Af, BfA, BfB, WfGd, bdg, hf, zf,
                                             Wdg, gq, (c == 0) ? 0 : 2, Wp, bp, rs, gq, 1);
        fused_cand<<<256, 256, 0, stream>>>(Af, BfB, BfA, WfCd, bdu, zf, hf,
                                            Wdu, gq, (c == 0) ? 0 : 1, Wp, bp, out, c, hor, 1);
    }
}

// Round 23
// 515.465 us; speedup vs baseline: 1.0375x; 1.0375x over previous
//
#include <hip/hip_runtime.h>
#include <hip/hip_bf16.h>
#include <math.h>

#define BB 32
#define TT 12
#define NN 512
#define HH 64
#define DIN 65
#define MSUB 96
#define RTOT 16384
#define PSUB 5
#define BSTG 10240     // f16 per B staging buffer (20 subtiles x 512), BK=128
#define WOFF 30720     // 3*BSTG: W region base (f16 units)

typedef _Float16 f16;
typedef f16 f16x4 __attribute__((ext_vector_type(4)));
typedef f16 f16x8 __attribute__((ext_vector_type(8)));
typedef float f32x4 __attribute__((ext_vector_type(4)));

#define GLD_LDS16(g, l) \
    __builtin_amdgcn_global_load_lds((const __attribute__((address_space(1))) void*)(g), \
                                     (__attribute__((address_space(3))) void*)(l), 16, 0, 0)

__device__ __forceinline__ size_t bf_addr(int j, int b, int p) {
    return ((size_t)(((j >> 5) * 32 + b) * PSUB + (p >> 4)) * 64 + ((j >> 3) & 3) * 16 + (p & 15)) * 8 + (j & 7);
}

__global__ __launch_bounds__(256) void conv_a(const float* __restrict__ P, f16* __restrict__ Af) {
    int u = blockIdx.x * 256 + threadIdx.x;
    int lane = u & 63;
    int su = u >> 6;
    int ks = su / MSUB, ms = su - ks * MSUB;
    int m = ms * 16 + (lane & 15);
    int k = ks * 32 + (lane >> 4) * 8;
    const float* src = &P[(size_t)m * 512 + k];
    f16x8 v;
#pragma unroll
    for (int i = 0; i < 8; ++i) v[i] = (f16)src[i];
    *(f16x8*)&Af[(size_t)u * 8] = v;
}

__global__ __launch_bounds__(256) void conv_w(const float* __restrict__ W, int O, int OS,
                                              f16* __restrict__ Wf) {
    int u = blockIdx.x * 256 + threadIdx.x;
    if (u >= 8 * OS * 64) return;
    int lane = u & 63, slot = u >> 6;
    int s = slot / OS, os = slot - s * OS;
    int o = os * 16 + (lane & 15);
    int g = lane >> 4;
    f16x8 v;
#pragma unroll
    for (int i = 0; i < 8; ++i) {
        int f = 2 * s + (i >= 4 ? 1 : 0);
        int kl = f / 5, ps = f - kl * 5;
        int p = ps * 16 + 4 * g + (i & 3);
        v[i] = (f < 15 && p < 65) ? (f16)W[(size_t)(kl * 65 + p) * O + o] : (f16)0.f;
    }
    *(f16x8*)&Wf[(size_t)u * 8] = v;
}

__global__ __launch_bounds__(256) void upd_x(const float* __restrict__ x, int t,
                                             f16* __restrict__ Bf) {
    int idx = blockIdx.x * 256 + threadIdx.x;
    if (idx >= RTOT) return;
    int b = idx >> 9, n = idx & 511;
    Bf[bf_addr(n, b, 0)] = (f16)x[((size_t)b * TT + t) * NN + n];
}

// B staging: 20 subtiles (K128-step), uniform 5 per wave
__device__ __forceinline__ void stage_b(const f16* __restrict__ BfIn, f16* __restrict__ lds,
                                        int b, int wave, int lane, int buf, int it) {
#pragma unroll
    for (int qi = 0; qi < 5; ++qi) {
        int q = qi * 4 + wave;  // 0..19
        int ksl = q / 5, ps = q - ksl * 5;
        const f16* src = &BfIn[((size_t)(((it * 4 + ksl) * 32 + b) * PSUB + ps) * 64 + lane) * 8];
        GLD_LDS16(src, &lds[buf * BSTG + q * 512 + lane * 8]);
    }
}

// A fragments for one K128-step: 12 per wave, direct global->VGPR
__device__ __forceinline__ void load_a(const f16* __restrict__ Af, f16x8 (&a)[12],
                                       int mb, int wave, int lane, int it) {
#pragma unroll
    for (int s = 0; s < 4; ++s)
#pragma unroll
        for (int k = 0; k < 3; ++k)
            a[s * 3 + k] = *(const f16x8*)&Af[((size_t)((it * 4 + s) * MSUB + k * 32 + mb * 4 + wave) * 64 + lane) * 8];
}

__device__ __forceinline__ void compute_step(const f16* __restrict__ lds, int buf, int lane,
                                             const f16x8 (&a)[12], f32x4 (&acc)[15]) {
#pragma unroll
    for (int s = 0; s < 4; ++s) {
        f16x8 bfr[5];
#pragma unroll
        for (int ps = 0; ps < 5; ++ps)
            bfr[ps] = *(const f16x8*)&lds[buf * BSTG + (s * 5 + ps) * 512 + lane * 8];
#pragma unroll
        for (int k = 0; k < 3; ++k)
#pragma unroll
            for (int ps = 0; ps < 5; ++ps)
                acc[k * 5 + ps] = __builtin_amdgcn_mfma_f32_16x16x32_f16(bfr[ps], a[s * 3 + k], acc[k * 5 + ps], 0, 0, 0);
    }
}

// BK=128: 4 K-steps, 3-buffer staging, counted vmcnt, one raw barrier per step.
__device__ __forceinline__ void gcn_mm(const f16* __restrict__ Af,
                                       const f16* __restrict__ BfIn,
                                       f16* __restrict__ lds,
                                       int b, int mb, int wave, int lane,
                                       f32x4 (&acc)[15]) {
    f16x8 a0[12], a1[12];
    stage_b(BfIn, lds, b, wave, lane, 0, 0);
    stage_b(BfIn, lds, b, wave, lane, 1, 1);
    load_a(Af, a0, mb, wave, lane, 0);
#pragma unroll
    for (int it = 0; it < 4; ++it) {
        asm volatile("s_waitcnt vmcnt(12)" ::: "memory");
        __builtin_amdgcn_sched_barrier(0);
        __builtin_amdgcn_s_barrier();
        __builtin_amdgcn_sched_barrier(0);
        if (it + 2 < 4) stage_b(BfIn, lds, b, wave, lane, (it + 2) % 3, it + 2);
        if (it + 1 < 4) {
            if ((it + 1) % 2 == 0) load_a(Af, a0, mb, wave, lane, it + 1);
            else                   load_a(Af, a1, mb, wave, lane, it + 1);
        }
        __builtin_amdgcn_sched_barrier(0);
        if (it % 2 == 0) compute_step(lds, it % 3, lane, a0, acc);
        else             compute_step(lds, it % 3, lane, a1, acc);
    }
}

__device__ __forceinline__ void build_ad(const f32x4 (&acc)[15], f16x8 (&ad)[8]) {
#pragma unroll
    for (int s = 0; s < 8; ++s)
#pragma unroll
        for (int i = 0; i < 4; ++i) {
            ad[s][i] = (f16)acc[2 * s][i];
            ad[s][4 + i] = (s < 7) ? (f16)acc[2 * s + 1][i] : (f16)0.f;
        }
}

// blockIdx = mb*32 + b: XCD = b%8, so Bf rows for batch b stay XCD-local across phases.
__global__ __launch_bounds__(256, 1) void fused_gates(const f16* __restrict__ Af,
                                                      const f16* __restrict__ BfIn,
                                                      f16* __restrict__ BfOut,
                                                      const f16* __restrict__ Wf,
                                                      const float* __restrict__ bias,
                                                      const float* __restrict__ hf,
                                                      float* __restrict__ zf) {
    __shared__ f16 lds[WOFF + 32768];
    int tid = threadIdx.x, wave = tid >> 6, lane = tid & 63;
    int b = blockIdx.x & 31, mb = blockIdx.x >> 5;

    // pre-stage W at entry: latency hides under the whole mm
#pragma unroll
    for (int qi = 0; qi < 16; ++qi) {
        int q = qi * 4 + wave;
        GLD_LDS16(&Wf[((size_t)q * 64 + lane) * 8], &lds[WOFF + q * 512 + lane * 8]);
    }

    f32x4 acc[15] = {};
    gcn_mm(Af, BfIn, lds, b, mb, wave, lane, acc);

    f16x8 ad[8];
    build_ad(acc, ad);

    f32x4 acc2[8] = {};
#pragma unroll
    for (int s = 0; s < 8; ++s)
#pragma unroll
        for (int os = 0; os < 8; ++os) {
            f16x8 w = *(const f16x8*)&lds[WOFF + (s * 8 + os) * 512 + lane * 8];
            acc2[os] = __builtin_amdgcn_mfma_f32_16x16x32_f16(ad[s], w, acc2[os], 0, 0, 0);
        }

    int o_l = lane & 15, g = lane >> 4;
    int node0 = mb * 64 + wave * 16;
    int rf = b * 32 + mb * 4 + wave;
#pragma unroll
    for (int os = 0; os < 4; ++os) {
        f32x4 v;
#pragma unroll
        for (int rI = 0; rI < 4; ++rI)
            v[rI] = 1.f / (1.f + expf(-(acc2[os][rI] + bias[os * 16 + o_l])));
        *(f32x4*)&zf[((size_t)(rf * 4 + os) * 64 + lane) * 4] = v;
    }
#pragma unroll
    for (int os = 4; os < 8; ++os) {
        int osh = os - 4;
        f32x4 hv = *(const f32x4*)&hf[((size_t)(rf * 4 + osh) * 64 + lane) * 4];
        f16x4 st;
#pragma unroll
        for (int rI = 0; rI < 4; ++rI) {
            float rr = 1.f / (1.f + expf(-(acc2[os][rI] + bias[64 + osh * 16 + o_l])));
            st[rI] = (f16)(rr * hv[rI]);
        }
        *(f16x4*)&BfOut[bf_addr(node0 + 4 * g, b, 1 + osh * 16 + o_l)] = st;
    }
    if (tid < 64) {
        int n = mb * 64 + tid;
        BfOut[bf_addr(n, b, 0)] = BfIn[bf_addr(n, b, 0)];
    }
}

__global__ __launch_bounds__(256, 1) void fused_cand(const f16* __restrict__ Af,
                                                     const f16* __restrict__ BfIn,
                                                     f16* __restrict__ BfOut,
                                                     const f16* __restrict__ Wf,
                                                     const float* __restrict__ bias,
                                                     const float* __restrict__ zf,
                                                     float* __restrict__ hf,
                                                     const float* __restrict__ xnext, int tnext,
                                                     const float* __restrict__ Wp,
                                                     const float* __restrict__ bp,
                                                     float* __restrict__ outp, int t, int hor,
                                                     int mode) {
    __shared__ f16 lds[WOFF + 16384];
    int tid = threadIdx.x, wave = tid >> 6, lane = tid & 63;
    int b = blockIdx.x & 31, mb = blockIdx.x >> 5;

#pragma unroll
    for (int qi = 0; qi < 8; ++qi) {
        int q = qi * 4 + wave;
        GLD_LDS16(&Wf[((size_t)q * 64 + lane) * 8], &lds[WOFF + q * 512 + lane * 8]);
    }

    f32x4 acc[15] = {};
    gcn_mm(Af, BfIn, lds, b, mb, wave, lane, acc);

    f16x8 ad[8];
    build_ad(acc, ad);

    f32x4 acc2[4] = {};
#pragma unroll
    for (int s = 0; s < 8; ++s)
#pragma unroll
        for (int os = 0; os < 4; ++os) {
            f16x8 w = *(const f16x8*)&lds[WOFF + (s * 4 + os) * 512 + lane * 8];
            acc2[os] = __builtin_amdgcn_mfma_f32_16x16x32_f16(ad[s], w, acc2[os], 0, 0, 0);
        }

    int o_l = lane & 15, g = lane >> 4;
    int node0 = mb * 64 + wave * 16;
    int rf = b * 32 + mb * 4 + wave;
    float pp[4] = {0.f, 0.f, 0.f, 0.f};
#pragma unroll
    for (int os = 0; os < 4; ++os) {
        int o = os * 16 + o_l;
        float wp = mode ? Wp[o] : 0.f;
        f32x4 zv = *(const f32x4*)&zf[((size_t)(rf * 4 + os) * 64 + lane) * 4];
        f32x4 hv = *(const f32x4*)&hf[((size_t)(rf * 4 + os) * 64 + lane) * 4];
        f32x4 hn;
        f16x4 st;
#pragma unroll
        for (int rI = 0; rI < 4; ++rI) {
            float hc = tanhf(acc2[os][rI] + bias[o]);
            hn[rI] = (1.f - zv[rI]) * hv[rI] + zv[rI] * hc;
            pp[rI] += hn[rI] * wp;
            st[rI] = (f16)hn[rI];
        }
        *(f32x4*)&hf[((size_t)(rf * 4 + os) * 64 + lane) * 4] = hn;
        *(f16x4*)&BfOut[bf_addr(node0 + 4 * g, b, 1 + o)] = st;
    }
    if (mode) {
#pragma unroll
        for (int m = 1; m < 16; m <<= 1)
#pragma unroll
            for (int rI = 0; rI < 4; ++rI) pp[rI] += __shfl_xor(pp[rI], m, 64);
        if (o_l == 0) {
            int n0 = node0 + 4 * g;
            float4 ov;
            f16x4 pv;
            ov.x = pp[0] + bp[0]; ov.y = pp[1] + bp[0];
            ov.z = pp[2] + bp[0]; ov.w = pp[3] + bp[0];
            pv[0] = (f16)ov.x; pv[1] = (f16)ov.y; pv[2] = (f16)ov.z; pv[3] = (f16)ov.w;
            *(float4*)&outp[((size_t)b * hor + t) * NN + n0] = ov;
            *(f16x4*)&BfOut[bf_addr(n0, b, 0)] = pv;
        }
    } else {
        if (o_l == 0) {
            int n0 = node0 + 4 * g;
            f16x4 pv;
#pragma unroll
            for (int rI = 0; rI < 4; ++rI)
                pv[rI] = (f16)(xnext ? xnext[((size_t)b * TT + tnext) * NN + n0 + rI] : 0.f);
            *(f16x4*)&BfOut[bf_addr(n0, b, 0)] = pv;
        }
    }
}

extern "C" void kernel_launch(void* const* d_in, const int* in_sizes, int n_in,
                              void* d_out, int out_size, void* d_ws, size_t ws_size,
                              hipStream_t stream) {
    const float* x   = (const float*)d_in[0];
    const float* P   = (const float*)d_in[1];
    const float* Weg = (const float*)d_in[2];
    const float* beg = (const float*)d_in[3];
    const float* Weu = (const float*)d_in[4];
    const float* beu = (const float*)d_in[5];
    const float* Wdg = (const float*)d_in[6];
    const float* bdg = (const float*)d_in[7];
    const float* Wdu = (const float*)d_in[8];
    const float* bdu = (const float*)d_in[9];
    const float* Wp  = (const float*)d_in[10];
    const float* bp  = (const float*)d_in[11];
    float* out = (float*)d_out;
    int hor = out_size / (BB * NN);

    float* ws = (float*)d_ws;
    size_t off = 0;
    float* hf = ws + off; off += (size_t)RTOT * HH;
    float* zf = ws + off; off += (size_t)RTOT * HH;
    f16* BfA  = (f16*)(ws + off); off += 16 * 32 * PSUB * 64 * 8 / 2;
    f16* BfB  = (f16*)(ws + off); off += 16 * 32 * PSUB * 64 * 8 / 2;
    f16* Af   = (f16*)(ws + off); off += (size_t)MSUB * 16 * 512 / 2;
    f16* WfGe = (f16*)(ws + off); off += 8 * 8 * 64 * 8 / 2;
    f16* WfGd = (f16*)(ws + off); off += 8 * 8 * 64 * 8 / 2;
    f16* WfCe = (f16*)(ws + off); off += 8 * 4 * 64 * 8 / 2;
    f16* WfCd = (f16*)(ws + off); off += 8 * 4 * 64 * 8 / 2;

    size_t bf_bytes = (size_t)16 * 32 * PSUB * 64 * 8 * sizeof(f16);
    hipMemsetAsync(hf, 0, (size_t)RTOT * HH * sizeof(float), stream);
    hipMemsetAsync(BfA, 0, bf_bytes, stream);
    hipMemsetAsync(BfB, 0, bf_bytes, stream);

    conv_a<<<(MSUB * 16 * 512 / 8) / 256, 256, 0, stream>>>(P, Af);
    conv_w<<<16, 256, 0, stream>>>(Weg, 128, 8, WfGe);
    conv_w<<<16, 256, 0, stream>>>(Wdg, 128, 8, WfGd);
    conv_w<<<8,  256, 0, stream>>>(Weu, 64, 4, WfCe);
    conv_w<<<8,  256, 0, stream>>>(Wdu, 64, 4, WfCd);
    upd_x<<<RTOT / 256, 256, 0, stream>>>(x, 0, BfA);

    for (int t = 0; t < TT; ++t) {
        fused_gates<<<256, 256, 0, stream>>>(Af, BfA, BfB, WfGe, beg, hf, zf);
        fused_cand<<<256, 256, 0, stream>>>(Af, BfB, BfA, WfCe, beu, zf, hf,
                                            (t + 1 < TT) ? x : nullptr, t + 1,
                                            nullptr, nullptr, nullptr, 0, hor, 0);
    }
    for (int t = 0; t < hor; ++t) {
        fused_gates<<<256, 256, 0, stream>>>(Af, BfA, BfB, WfGd, bdg, hf, zf);
        fused_cand<<<256, 256, 0, stream>>>(Af, BfB, BfA, WfCd, bdu, zf, hf,
                                            nullptr, 0,
                                            Wp, bp, out, t, hor, 1);
    }
}